// Round 1
// baseline (185.556 us; speedup 1.0000x reference)
//
#include <hip/hip_runtime.h>
#include <math.h>

typedef short   s16x8  __attribute__((ext_vector_type(8)));
typedef __bf16  bf16x8 __attribute__((ext_vector_type(8)));
typedef float   f32x4  __attribute__((ext_vector_type(4)));

#define T_FREQ 169
#define NN     336      // L == n (output length)
#define CCH    512
#define BB     32
#define TP     176      // t padded to 11*16 (stage A M)
#define LP     352      // L padded to 11*32 (stage A K)
#define KP     192      // t padded to 6*32  (stage C K)

// ---- workspace layout (bytes), all offsets 16B-aligned ----
static constexpr size_t OFF_COEF = 0;                                  // 169 f32
static constexpr size_t OFF_FC   = 1024;                               // [176][352] bf16 (cos/sqrt(n))
static constexpr size_t OFF_FS   = OFF_FC + 124928;                    // [176][352] bf16 (-sin/sqrt(n))
static constexpr size_t OFF_CCOS = OFF_FS + 124928;                    // [336][192] bf16 cos
static constexpr size_t OFF_CSIN = OFF_CCOS + 130048;                  // [336][192] bf16 -sin
static constexpr size_t OFF_XT   = OFF_CSIN + 130048;                  // [32][512][352] bf16 (x transposed)
static constexpr size_t OFF_XR   = OFF_XT + (size_t)BB*CCH*LP*2;       // [176][32][512] bf16
static constexpr size_t OFF_XI   = OFF_XR + (size_t)TP*BB*CCH*2;       // [176][32][512] bf16
static constexpr size_t OFF_Y    = OFF_XI + (size_t)TP*BB*CCH*2;       // [32][192][512] (bf16 r, bf16 i) packed u32

__device__ __forceinline__ unsigned short f2bf(float f){
  unsigned u = __builtin_bit_cast(unsigned, f);
  u = (u + 0x7fffu + ((u >> 16) & 1u)) >> 16;   // round-to-nearest-even
  return (unsigned short)u;
}

__device__ __forceinline__ f32x4 mfma16(bf16x8 a, bf16x8 b, f32x4 c){
  return __builtin_amdgcn_mfma_f32_16x16x32_bf16(a, b, c, 0, 0, 0);
}

// ---------------- P1: coef softmax + twiddle tables ----------------
__global__ __launch_bounds__(256) void prep_tables(const float* __restrict__ wts, char* ws){
  float* coef = (float*)(ws + OFF_COEF);
  unsigned short* Fc  = (unsigned short*)(ws + OFF_FC);
  unsigned short* Fs  = (unsigned short*)(ws + OFF_FS);
  unsigned short* Cc  = (unsigned short*)(ws + OFF_CCOS);
  unsigned short* Cs  = (unsigned short*)(ws + OFF_CSIN);
  const float PI2_N = 6.283185307179586f / (float)NN;
  const float inv_sqrt_n = 0.05455447255899809f;  // 1/sqrt(336)

  if (blockIdx.x == 0){
    __shared__ float red[256];
    int tid = threadIdx.x;
    float v = (tid < T_FREQ) ? wts[tid] : -1e30f;
    red[tid] = v; __syncthreads();
    for (int s = 128; s > 0; s >>= 1){ if (tid < s) red[tid] = fmaxf(red[tid], red[tid+s]); __syncthreads(); }
    float mx = red[0]; __syncthreads();
    float e = (tid < T_FREQ) ? expf(v - mx) : 0.f;
    red[tid] = e; __syncthreads();
    for (int s = 128; s > 0; s >>= 1){ if (tid < s) red[tid] += red[tid+s]; __syncthreads(); }
    float ssum = red[0];
    if (tid < T_FREQ){
      float sc = (tid == 0 || tid == T_FREQ-1) ? 1.f : 2.f;
      coef[tid] = (e / ssum) * sc * inv_sqrt_n;
    }
    return;
  }
  int gid = (blockIdx.x - 1) * 256 + threadIdx.x;
  int stride = (gridDim.x - 1) * 256;
  // forward DFT matrices [TP][LP]: Fc = cos(th)/sqrt(n), Fs = -sin(th)/sqrt(n)
  for (int e = gid; e < TP*LP; e += stride){
    int i = e / LP, l = e % LP;
    float c = 0.f, s = 0.f;
    if (l < NN){
      int m = (i * l) % NN;
      float sv, cv; sincosf(PI2_N * (float)m, &sv, &cv);
      c = cv * inv_sqrt_n; s = -sv * inv_sqrt_n;
    }
    Fc[e] = f2bf(c); Fs[e] = f2bf(s);
  }
  // inverse projection matrices [NN][KP]: Cc = cos, Cs = -sin (zero-padded i>=169)
  for (int e = gid; e < NN*KP; e += stride){
    int l = e / KP, i = e % KP;
    float c = 0.f, s = 0.f;
    if (i < T_FREQ){
      int m = (i * l) % NN;
      float sv, cv; sincosf(PI2_N * (float)m, &sv, &cv);
      c = cv; s = -sv;
    }
    Cc[e] = f2bf(c); Cs[e] = f2bf(s);
  }
}

// ---------------- P2: x [b][l][c] f32 -> x_t [b][c][l] bf16 (l zero-padded to 352) ----------------
__global__ __launch_bounds__(256) void transpose_x(const float* __restrict__ x, char* ws){
  unsigned short* xt = (unsigned short*)(ws + OFF_XT);
  __shared__ float tile[32][33];
  int bid = blockIdx.x;
  int b  = bid / (11*16);
  int rm = bid % (11*16);
  int lt = rm / 16, ct = rm % 16;
  int tx = threadIdx.x & 31, ty = threadIdx.x >> 5;   // 32 x 8
  #pragma unroll
  for (int k = 0; k < 4; ++k){
    int l = lt*32 + ty + k*8;
    int c = ct*32 + tx;
    float v = (l < NN) ? x[((size_t)b*NN + l)*CCH + c] : 0.f;
    tile[ty + k*8][tx] = v;
  }
  __syncthreads();
  #pragma unroll
  for (int k = 0; k < 4; ++k){
    int crow = ct*32 + ty + k*8;
    int lcol = lt*32 + tx;
    xt[((size_t)b*CCH + crow)*LP + lcol] = f2bf(tile[tx][ty + k*8]);
  }
}

// ---------------- Stage A: rfft as GEMM. Xr/Xi[i][b][c] = sum_l F[i][l] * x_t[b][c][l] ----------------
__global__ __launch_bounds__(256) void stage_rfft(char* ws){
  const unsigned short* xt = (const unsigned short*)(ws + OFF_XT);
  const unsigned short* Fc = (const unsigned short*)(ws + OFF_FC);
  const unsigned short* Fs = (const unsigned short*)(ws + OFF_FS);
  unsigned short* xr = (unsigned short*)(ws + OFF_XR);
  unsigned short* xi = (unsigned short*)(ws + OFF_XI);

  int b  = blockIdx.x >> 3;
  int c0 = (blockIdx.x & 7) * 64;
  int tid = threadIdx.x, lane = tid & 63, wv = tid >> 6;
  int kg = lane >> 4, ln = lane & 15;
  int c = c0 + wv*16 + ln;

  f32x4 aR[11], aI[11];
  #pragma unroll
  for (int m = 0; m < 11; ++m){ aR[m] = (f32x4){0,0,0,0}; aI[m] = (f32x4){0,0,0,0}; }

  const unsigned short* xrow = xt + ((size_t)b*CCH + c)*LP;
  for (int kk = 0; kk < 11; ++kk){
    int ko = kk*32 + kg*8;
    bf16x8 bx = *(const bf16x8*)(xrow + ko);
    #pragma unroll
    for (int m = 0; m < 11; ++m){
      bf16x8 fc = *(const bf16x8*)(Fc + (size_t)(m*16 + ln)*LP + ko);
      bf16x8 fs = *(const bf16x8*)(Fs + (size_t)(m*16 + ln)*LP + ko);
      aR[m] = mfma16(fc, bx, aR[m]);
      aI[m] = mfma16(fs, bx, aI[m]);
    }
  }
  int rbase = kg*4;
  #pragma unroll
  for (int m = 0; m < 11; ++m){
    #pragma unroll
    for (int r = 0; r < 4; ++r){
      int i = m*16 + rbase + r;
      size_t off = ((size_t)i*BB + b)*CCH + c;
      xr[off] = f2bf(aR[m][r]);
      xi[off] = f2bf(aI[m][r]);
    }
  }
}

// ---------------- Stage B: per-frequency complex GEMM (HBM-bound W stream) ----------------
__global__ __launch_bounds__(256) void stage_cgemm(const float* __restrict__ Wr, const float* __restrict__ Wi,
                                                   const float* __restrict__ br, const float* __restrict__ bi,
                                                   char* ws){
  const unsigned short* xr = (const unsigned short*)(ws + OFF_XR);
  const unsigned short* xi = (const unsigned short*)(ws + OFF_XI);
  const float* coef = (const float*)(ws + OFF_COEF);
  unsigned int* y = (unsigned int*)(ws + OFF_Y);

  int i  = blockIdx.x >> 2;
  int nb = blockIdx.x & 3;
  int tid = threadIdx.x, lane = tid & 63, wv = tid >> 6;
  int kg = lane >> 4, ln = lane & 15;
  int o0 = nb*128 + wv*32;

  f32x4 accR[2][2], accI[2][2];
  #pragma unroll
  for (int m = 0; m < 2; ++m)
    #pragma unroll
    for (int n = 0; n < 2; ++n){ accR[m][n] = (f32x4){0,0,0,0}; accI[m][n] = (f32x4){0,0,0,0}; }

  const size_t wbase = (size_t)i * CCH * CCH;
  const size_t xbase = (size_t)i * BB * CCH;

  for (int kk = 0; kk < 16; ++kk){
    int ko = kk*32 + kg*8;
    bf16x8 ar[2], ai[2];
    #pragma unroll
    for (int mb = 0; mb < 2; ++mb){
      ar[mb] = *(const bf16x8*)(xr + xbase + (size_t)(mb*16 + ln)*CCH + ko);
      ai[mb] = *(const bf16x8*)(xi + xbase + (size_t)(mb*16 + ln)*CCH + ko);
    }
    #pragma unroll
    for (int nt = 0; nt < 2; ++nt){
      const float* wrp = Wr + wbase + (size_t)(o0 + nt*16 + ln)*CCH + ko;
      const float* wip = Wi + wbase + (size_t)(o0 + nt*16 + ln)*CCH + ko;
      float4 r0 = *(const float4*)(wrp);
      float4 r1 = *(const float4*)(wrp + 4);
      float4 i0 = *(const float4*)(wip);
      float4 i1 = *(const float4*)(wip + 4);
      s16x8 tr, ti;
      tr[0]=f2bf(r0.x); tr[1]=f2bf(r0.y); tr[2]=f2bf(r0.z); tr[3]=f2bf(r0.w);
      tr[4]=f2bf(r1.x); tr[5]=f2bf(r1.y); tr[6]=f2bf(r1.z); tr[7]=f2bf(r1.w);
      ti[0]=f2bf(i0.x); ti[1]=f2bf(i0.y); ti[2]=f2bf(i0.z); ti[3]=f2bf(i0.w);
      ti[4]=f2bf(i1.x); ti[5]=f2bf(i1.y); ti[6]=f2bf(i1.z); ti[7]=f2bf(i1.w);
      s16x8 tin = ti ^ (short)0x8000;              // -Wi
      bf16x8 bwr  = __builtin_bit_cast(bf16x8, tr);
      bf16x8 bwi  = __builtin_bit_cast(bf16x8, ti);
      bf16x8 bwin = __builtin_bit_cast(bf16x8, tin);
      #pragma unroll
      for (int mb = 0; mb < 2; ++mb){
        accR[mb][nt] = mfma16(ar[mb], bwr,  accR[mb][nt]);  // xr*Wr
        accR[mb][nt] = mfma16(ai[mb], bwin, accR[mb][nt]);  // -xi*Wi
        accI[mb][nt] = mfma16(ar[mb], bwi,  accI[mb][nt]);  // xr*Wi
        accI[mb][nt] = mfma16(ai[mb], bwr,  accI[mb][nt]);  // xi*Wr
      }
    }
  }

  float cf = coef[i];
  #pragma unroll
  for (int nt = 0; nt < 2; ++nt){
    int o = o0 + nt*16 + ln;
    float fbr = br[(size_t)i*CCH + o];
    float fbi = bi[(size_t)i*CCH + o];
    #pragma unroll
    for (int mb = 0; mb < 2; ++mb){
      #pragma unroll
      for (int r = 0; r < 4; ++r){
        float vr = (accR[mb][nt][r] + fbr) * cf;
        float vi = (accI[mb][nt][r] + fbi) * cf;
        int bb = mb*16 + kg*4 + r;
        y[((size_t)bb*KP + i)*CCH + o] = (unsigned)f2bf(vr) | ((unsigned)f2bf(vi) << 16);
      }
    }
  }
}

// ---------------- Stage C: out[b][l][c] = sum_i Cc[l][i]*yr[i][c] + Cs[l][i]*yi[i][c] ----------------
__global__ __launch_bounds__(256) void stage_irfft(const char* ws_c, float* __restrict__ out){
  const char* ws = ws_c;
  const unsigned short* Cc = (const unsigned short*)(ws + OFF_CCOS);
  const unsigned short* Cs = (const unsigned short*)(ws + OFF_CSIN);
  const unsigned int* y = (const unsigned int*)(ws + OFF_Y);

  __shared__ unsigned short lr[64][40];   // [c][i] transposed tile, 16B-aligned rows
  __shared__ unsigned short li[64][40];

  int b  = blockIdx.x >> 3;
  int c0 = (blockIdx.x & 7) * 64;
  int tid = threadIdx.x, lane = tid & 63, wv = tid >> 6;
  int kg = lane >> 4, ln = lane & 15;

  f32x4 acc[21];
  #pragma unroll
  for (int m = 0; m < 21; ++m) acc[m] = (f32x4){0,0,0,0};

  for (int kk = 0; kk < 6; ++kk){
    if (kk) __syncthreads();
    #pragma unroll
    for (int q = 0; q < 8; ++q){
      int idx = q*256 + tid;
      int ir = idx >> 6, cc = idx & 63;
      int i = kk*32 + ir;
      unsigned u = (i < T_FREQ) ? y[((size_t)b*KP + i)*CCH + c0 + cc] : 0u;
      lr[cc][ir] = (unsigned short)(u & 0xffffu);
      li[cc][ir] = (unsigned short)(u >> 16);
    }
    __syncthreads();
    int ko = kk*32 + kg*8;
    bf16x8 blr = *(const bf16x8*)(&lr[wv*16 + ln][kg*8]);
    bf16x8 bli = *(const bf16x8*)(&li[wv*16 + ln][kg*8]);
    #pragma unroll
    for (int m = 0; m < 21; ++m){
      bf16x8 ac = *(const bf16x8*)(Cc + (size_t)(m*16 + ln)*KP + ko);
      bf16x8 as = *(const bf16x8*)(Cs + (size_t)(m*16 + ln)*KP + ko);
      acc[m] = mfma16(ac, blr, acc[m]);
      acc[m] = mfma16(as, bli, acc[m]);
    }
  }

  int cdst = c0 + wv*16 + ln;
  #pragma unroll
  for (int m = 0; m < 21; ++m){
    #pragma unroll
    for (int r = 0; r < 4; ++r){
      int l = m*16 + kg*4 + r;
      out[((size_t)b*NN + l)*CCH + cdst] = acc[m][r];
    }
  }
}

extern "C" void kernel_launch(void* const* d_in, const int* in_sizes, int n_in,
                              void* d_out, int out_size, void* d_ws, size_t ws_size,
                              hipStream_t stream){
  const float* x   = (const float*)d_in[0];
  const float* Wr  = (const float*)d_in[1];
  const float* Wi  = (const float*)d_in[2];
  const float* br  = (const float*)d_in[3];
  const float* bi  = (const float*)d_in[4];
  const float* wts = (const float*)d_in[5];
  char* ws = (char*)d_ws;

  prep_tables<<<257, 256, 0, stream>>>(wts, ws);
  transpose_x<<<32*11*16, 256, 0, stream>>>(x, ws);
  stage_rfft<<<256, 256, 0, stream>>>(ws);
  stage_cgemm<<<T_FREQ*4, 256, 0, stream>>>(Wr, Wi, br, bi, ws);
  stage_irfft<<<256, 256, 0, stream>>>(ws, (float*)d_out);
}